// Round 2
// baseline (304.639 us; speedup 1.0000x reference)
//
#include <hip/hip_runtime.h>
#include <hip/hip_bf16.h>
#include <cmath>
#include <stdint.h>

using bf16 = __hip_bfloat16;
typedef __attribute__((ext_vector_type(8))) short bf16x8;
typedef __attribute__((ext_vector_type(4))) float f32x4;

// R=128, N=256, B=1, E=512, H=8, D=64, M=4
constexpr long HS  = 2097152;  // per-head stride: N * (R*D) = 256*8192
constexpr int  LDT = 40;       // LDS row stride (bf16): 80B rows, ~2-way bank aliasing (free)

// ---------------- QKV projection, fused scatter-transpose epilogue ----------------
// X [32768,512] fp32 row-major; WT [1536,512] bf16 (pre-transposed, Q-scaled).
// Writes Qt/Kt [h][i][r*64+d], Qu = Qt*u[d], Vj [h][r*64+d][i].
__global__ __launch_bounds__(512)
void gemm_qkv(const float* __restrict__ X, const bf16* __restrict__ WT,
              const float* __restrict__ bias_all, const float* __restrict__ u,
              bf16* __restrict__ Qt, bf16* __restrict__ Kt,
              bf16* __restrict__ Qu, bf16* __restrict__ Vj)
{
  __shared__ bf16 As[128 * LDT];
  __shared__ bf16 Bs[256 * LDT];
  __shared__ float us[64];
  const int tid = threadIdx.x, lane = tid & 63, wid = tid >> 6;
  const int wr = wid >> 2, wc = wid & 3;          // 8 waves = 2(m) x 4(n)
  const int lr = lane & 15, lk = (lane >> 4) * 8;
  const int m0 = blockIdx.y * 128, n0 = blockIdx.x * 256;
  if (tid < 64) us[tid] = u[tid];
  f32x4 acc[4][4] = {};

  for (int k0 = 0; k0 < 512; k0 += 32) {
    {  // A tile: fp32 -> bf16 on the fly. 512 chunks of 8, one per thread.
      const int r = tid >> 2, k8 = (tid & 3) * 8;
      const float4 f0 = *(const float4*)&X[(long)(m0 + r) * 512 + k0 + k8];
      const float4 f1 = *(const float4*)&X[(long)(m0 + r) * 512 + k0 + k8 + 4];
      alignas(16) bf16 t[8] = {
        __float2bfloat16(f0.x), __float2bfloat16(f0.y),
        __float2bfloat16(f0.z), __float2bfloat16(f0.w),
        __float2bfloat16(f1.x), __float2bfloat16(f1.y),
        __float2bfloat16(f1.z), __float2bfloat16(f1.w)};
      *(uint4*)&As[r * LDT + k8] = *(const uint4*)t;
    }
    #pragma unroll
    for (int c = tid; c < 1024; c += 512) {  // B tile: 256 rows x 32
      const int r = c >> 2, k8 = (c & 3) * 8;
      *(uint4*)&Bs[r * LDT + k8] = *(const uint4*)&WT[(long)(n0 + r) * 512 + k0 + k8];
    }
    __syncthreads();
    bf16x8 af[4], bfr[4];
    #pragma unroll
    for (int m = 0; m < 4; m++)
      af[m] = *(const bf16x8*)&As[(wr * 64 + m * 16 + lr) * LDT + lk];
    #pragma unroll
    for (int n = 0; n < 4; n++)
      bfr[n] = *(const bf16x8*)&Bs[(wc * 64 + n * 16 + lr) * LDT + lk];
    #pragma unroll
    for (int m = 0; m < 4; m++)
      #pragma unroll
      for (int n = 0; n < 4; n++)
        acc[m][n] = __builtin_amdgcn_mfma_f32_16x16x32_bf16(af[m], bfr[n], acc[m][n], 0, 0, 0);
    __syncthreads();
  }

  const int er = (lane >> 4) * 4, ec = lane & 15;
  #pragma unroll
  for (int m = 0; m < 4; m++) {
    const int row0 = m0 + wr * 64 + m * 16 + er;  // = r*256 + i0, i0..i0+3 consecutive
    const int r = row0 >> 8, i0 = row0 & 255;
    #pragma unroll
    for (int n = 0; n < 4; n++) {
      const int col = n0 + wc * 64 + n * 16 + ec;
      const int which = col >> 9, h = (col >> 6) & 7, d = col & 63;
      const float bv = bias_all[col];
      const float v0 = acc[m][n][0] + bv, v1 = acc[m][n][1] + bv;
      const float v2 = acc[m][n][2] + bv, v3 = acc[m][n][3] + bv;
      const long base = (long)h * HS;
      if (which == 0) {
        const float uu = us[d];
        const long p = base + (long)i0 * 8192 + r * 64 + d;
        Qt[p]            = __float2bfloat16(v0); Qu[p]            = __float2bfloat16(v0 * uu);
        Qt[p + 8192]     = __float2bfloat16(v1); Qu[p + 8192]     = __float2bfloat16(v1 * uu);
        Qt[p + 16384]    = __float2bfloat16(v2); Qu[p + 16384]    = __float2bfloat16(v2 * uu);
        Qt[p + 24576]    = __float2bfloat16(v3); Qu[p + 24576]    = __float2bfloat16(v3 * uu);
      } else if (which == 1) {
        const long p = base + (long)i0 * 8192 + r * 64 + d;
        Kt[p]         = __float2bfloat16(v0);
        Kt[p + 8192]  = __float2bfloat16(v1);
        Kt[p + 16384] = __float2bfloat16(v2);
        Kt[p + 24576] = __float2bfloat16(v3);
      } else {
        alignas(8) bf16 t4[4] = {__float2bfloat16(v0), __float2bfloat16(v1),
                                 __float2bfloat16(v2), __float2bfloat16(v3)};
        *(uint2*)&Vj[base + (long)(r * 64 + d) * 256 + i0] = *(const uint2*)t4;
      }
    }
  }
}

// ---------------- logits: 16 batches (8 attn heads + 8 u-scaled), split-K=4 ----------------
// part[z=batch*4+ks][i*256+j] = sum_{k in slice} A[i,k]*B[j,k], lda=ldb=8192
__global__ __launch_bounds__(256)
void gemm_logits(const bf16* __restrict__ Qt, const bf16* __restrict__ Qu,
                 const bf16* __restrict__ Kt, float* __restrict__ part)
{
  __shared__ bf16 As[128 * LDT];
  __shared__ bf16 Bs[128 * LDT];
  const int z = blockIdx.z, batch = z >> 2, ks = z & 3;
  const bf16* A = (batch < 8 ? Qt + (long)batch * HS : Qu + (long)(batch - 8) * HS) + ks * 2048;
  const bf16* B = Kt + (long)(batch & 7) * HS + ks * 2048;
  const int m0 = blockIdx.y * 128, n0 = blockIdx.x * 128;
  const int tid = threadIdx.x, lane = tid & 63, wid = tid >> 6;
  const int wr = wid >> 1, wc = wid & 1;
  const int lr = lane & 15, lk = (lane >> 4) * 8;
  f32x4 acc[4][4] = {};

  for (int k0 = 0; k0 < 2048; k0 += 32) {
    #pragma unroll
    for (int c = tid; c < 512; c += 256) {
      const int r = c >> 2, k8 = (c & 3) * 8;
      *(uint4*)&As[r * LDT + k8] = *(const uint4*)&A[(long)(m0 + r) * 8192 + k0 + k8];
    }
    #pragma unroll
    for (int c = tid; c < 512; c += 256) {
      const int r = c >> 2, k8 = (c & 3) * 8;
      *(uint4*)&Bs[r * LDT + k8] = *(const uint4*)&B[(long)(n0 + r) * 8192 + k0 + k8];
    }
    __syncthreads();
    bf16x8 af[4], bfr[4];
    #pragma unroll
    for (int m = 0; m < 4; m++)
      af[m] = *(const bf16x8*)&As[(wr * 64 + m * 16 + lr) * LDT + lk];
    #pragma unroll
    for (int n = 0; n < 4; n++)
      bfr[n] = *(const bf16x8*)&Bs[(wc * 64 + n * 16 + lr) * LDT + lk];
    #pragma unroll
    for (int m = 0; m < 4; m++)
      #pragma unroll
      for (int n = 0; n < 4; n++)
        acc[m][n] = __builtin_amdgcn_mfma_f32_16x16x32_bf16(af[m], bfr[n], acc[m][n], 0, 0, 0);
    __syncthreads();
  }

  float* C = part + (long)z * 65536;
  const int er = (lane >> 4) * 4, ec = lane & 15;
  #pragma unroll
  for (int m = 0; m < 4; m++)
    #pragma unroll
    for (int n = 0; n < 4; n++) {
      const int col = n0 + wc * 64 + n * 16 + ec;
      #pragma unroll
      for (int q = 0; q < 4; q++) {
        const int row = m0 + wr * 64 + m * 16 + er + q;
        C[(long)row * 256 + col] = acc[m][n][q];
      }
    }
}

// ---------------- generic C = A*B^T GEMM (bf16 in), modes: 1 f32 store, 2 ctx scatter ----------------
template<int BM, int BN, int MODE>
__global__ __launch_bounds__((BM/64)*(BN/64)*64)
void gemm_bt(const bf16* __restrict__ A, const bf16* __restrict__ B,
             void* __restrict__ Cp, const float* __restrict__ bias,
             int K, int ldc, long sA, long sB, long sC)
{
  constexpr int NW = (BM/64)*(BN/64);
  constexpr int NT = NW * 64;
  constexpr int WC = BN/64;
  const int z = blockIdx.z;
  A += (long)z * sA;
  B += (long)z * sB;
  const int m0 = blockIdx.y * BM, n0 = blockIdx.x * BN;
  __shared__ bf16 As[BM * LDT];
  __shared__ bf16 Bs[BN * LDT];
  const int tid = threadIdx.x;
  const int lane = tid & 63, wid = tid >> 6;
  const int wr = wid / WC, wc = wid % WC;
  const int lr = lane & 15, lk = (lane >> 4) * 8;
  f32x4 acc[4][4] = {};

  for (int k0 = 0; k0 < K; k0 += 32) {
    for (int c = tid; c < BM * 4; c += NT) {
      const int r = c >> 2, k8 = (c & 3) * 8;
      *(uint4*)&As[r * LDT + k8] = *(const uint4*)&A[(long)(m0 + r) * K + k0 + k8];
    }
    for (int c = tid; c < BN * 4; c += NT) {
      const int r = c >> 2, k8 = (c & 3) * 8;
      *(uint4*)&Bs[r * LDT + k8] = *(const uint4*)&B[(long)(n0 + r) * K + k0 + k8];
    }
    __syncthreads();
    bf16x8 af[4], bfr[4];
    #pragma unroll
    for (int m = 0; m < 4; m++)
      af[m] = *(const bf16x8*)&As[(wr * 64 + m * 16 + lr) * LDT + lk];
    #pragma unroll
    for (int n = 0; n < 4; n++)
      bfr[n] = *(const bf16x8*)&Bs[(wc * 64 + n * 16 + lr) * LDT + lk];
    #pragma unroll
    for (int m = 0; m < 4; m++)
      #pragma unroll
      for (int n = 0; n < 4; n++)
        acc[m][n] = __builtin_amdgcn_mfma_f32_16x16x32_bf16(af[m], bfr[n], acc[m][n], 0, 0, 0);
    __syncthreads();
  }

  const int er = (lane >> 4) * 4, ec = lane & 15;
  #pragma unroll
  for (int m = 0; m < 4; m++) {
    #pragma unroll
    for (int n = 0; n < 4; n++) {
      const int col = n0 + wc * 64 + n * 16 + ec;
      const float bv = (MODE == 1 && bias != nullptr) ? bias[col] : 0.0f;
      #pragma unroll
      for (int q = 0; q < 4; q++) {
        const int row = m0 + wr * 64 + m * 16 + er + q;
        const float v = acc[m][n][q] + bv;
        if constexpr (MODE == 1) {
          ((float*)Cp)[z * sC + (long)row * ldc + col] = v;
        } else {
          const int rr = col >> 6, dd = col & 63;  // col = r*64+d, z = h
          ((bf16*)Cp)[(long)rr * 131072 + (long)row * 512 + z * 64 + dd] = __float2bfloat16(v);
        }
      }
    }
  }
}

// ---------------- weight prep: WT[n][k] = W[k][n] (Q cols pre-scaled), bias_all, u[d] ----------------
__global__ void k_prep_w(const float* __restrict__ Wq, const float* __restrict__ bq,
                         const float* __restrict__ Wk, const float* __restrict__ bk,
                         const float* __restrict__ Wv, const float* __restrict__ bv,
                         const float* __restrict__ Wo, const float* __restrict__ bo,
                         const float* __restrict__ Wq1, const float* __restrict__ Wk1,
                         bf16* __restrict__ WT, float* __restrict__ bias_all,
                         float* __restrict__ u, float scaling)
{
  const long idx = (long)blockIdx.x * 256 + threadIdx.x;  // 1,048,576 threads
  const int k = idx >> 11, n = idx & 2047;
  const int sel = n >> 9, nn = n & 511;
  const float* W = sel == 0 ? Wq : sel == 1 ? Wk : sel == 2 ? Wv : Wo;
  const float sc = sel == 0 ? scaling : 1.0f;
  WT[(long)n * 512 + k] = __float2bfloat16(W[k * 512 + nn] * sc);
  if (idx < 2048) {
    const int s2 = idx >> 9, n2 = idx & 511;
    const float* b = s2 == 0 ? bq : s2 == 1 ? bk : s2 == 2 ? bv : bo;
    bias_all[idx] = b[n2] * (s2 == 0 ? scaling : 1.0f);
  }
  if (idx < 64) {
    float s = 0.0f;
    #pragma unroll
    for (int c = 0; c < 8; c++) s += Wq1[idx * 8 + c] * Wk1[c];
    u[idx] = s;
  }
}

// ---------------- split-K reduce: logits[b][ij] = sum_ks part[b*4+ks][ij] ----------------
__global__ void k_reduce(const float* __restrict__ part, float* __restrict__ logits)
{
  const long t = (long)blockIdx.x * 256 + threadIdx.x;  // 262,144 threads x float4
  const long flat = t * 4;
  const long b = flat >> 16, ij = flat & 65535;
  float4 s = *(const float4*)&part[((b * 4 + 0) << 16) + ij];
  #pragma unroll
  for (int ks = 1; ks < 4; ks++) {
    const float4 p = *(const float4*)&part[((b * 4 + ks) << 16) + ij];
    s.x += p.x; s.y += p.y; s.z += p.z; s.w += p.w;
  }
  *(float4*)&logits[flat] = s;
}

// ---------------- network-bias branch: softmax over M of network*s1 ----------------
__global__ void k_bias(const float* __restrict__ logits, const float* __restrict__ network,
                       const float* __restrict__ bq1, const float* __restrict__ Wk1,
                       float* __restrict__ net_bias)
{
  const int i = blockIdx.x, j = threadIdx.x;
  float c1 = 0.0f;
  #pragma unroll
  for (int c = 0; c < 8; c++) c1 += bq1[c] * Wk1[c];
  float s1 = 0.0f;
  #pragma unroll
  for (int h = 0; h < 8; h++) s1 += logits[(long)(8 + h) * 65536 + i * 256 + j];
  s1 = 0.125f * s1 + c1;
  const float4 nw = *(const float4*)&network[(long)(i * 256 + j) * 4];
  const float a0 = nw.x * s1, a1 = nw.y * s1, a2 = nw.z * s1, a3 = nw.w * s1;
  const float mx = fmaxf(fmaxf(a0, a1), fmaxf(a2, a3));
  const float e0 = expf(a0 - mx), e1 = expf(a1 - mx), e2 = expf(a2 - mx), e3 = expf(a3 - mx);
  const float inv = 1.0f / (e0 + e1 + e2 + e3);
  net_bias[i * 256 + j] = (nw.x * e0 + nw.y * e1 + nw.z * e2 + nw.w * e3) * inv;
}

// ---------------- row softmax with eye mask; fp32 probs to d_out + bf16 copy ----------------
__global__ void k_softmax(const float* __restrict__ logits, const float* __restrict__ net_bias,
                          const float* __restrict__ l, float* __restrict__ out_probs,
                          bf16* __restrict__ Pb, float* __restrict__ out_l)
{
  const int i = blockIdx.x, h = blockIdx.y, j = threadIdx.x;
  float w = logits[(long)h * 65536 + i * 256 + j] + l[h] * net_bias[i * 256 + j];
  if (j == i) w = -1e9f;
  float m = w;
  #pragma unroll
  for (int o = 32; o; o >>= 1) m = fmaxf(m, __shfl_xor(m, o));
  __shared__ float red[4], red2[4];
  if ((j & 63) == 0) red[j >> 6] = m;
  __syncthreads();
  m = fmaxf(fmaxf(red[0], red[1]), fmaxf(red[2], red[3]));
  const float e = expf(w - m);
  float s = e;
  #pragma unroll
  for (int o = 32; o; o >>= 1) s += __shfl_xor(s, o);
  if ((j & 63) == 0) red2[j >> 6] = s;
  __syncthreads();
  s = red2[0] + red2[1] + red2[2] + red2[3];
  const float p = e / s;
  out_probs[(long)h * 65536 + i * 256 + j] = p;
  Pb[(long)h * 65536 + i * 256 + j] = __float2bfloat16(p);
  if (h == 0 && i == 0 && j < 8) out_l[j] = l[j];
}

extern "C" void kernel_launch(void* const* d_in, const int* in_sizes, int n_in,
                              void* d_out, int out_size, void* d_ws, size_t ws_size,
                              hipStream_t stream)
{
  const float* x   = (const float*)d_in[0];
  const float* net = (const float*)d_in[1];
  const float* Wq  = (const float*)d_in[2];
  const float* bq  = (const float*)d_in[3];
  const float* Wk  = (const float*)d_in[4];
  const float* bk  = (const float*)d_in[5];
  const float* Wv  = (const float*)d_in[6];
  const float* bv  = (const float*)d_in[7];
  const float* Wo  = (const float*)d_in[8];
  const float* bo  = (const float*)d_in[9];
  const float* Wq1 = (const float*)d_in[10];
  const float* bq1 = (const float*)d_in[11];
  const float* Wk1 = (const float*)d_in[12];
  const float* bk1 = (const float*)d_in[13];
  const float* l   = (const float*)d_in[14];
  (void)bk1;  // cancels in the M-softmax
  float* out = (float*)d_out;

  // Qt/Kt live in d_out[0 : 64MB] — dead before the final out-projection writes it.
  bf16* Qt = (bf16*)d_out;
  bf16* Kt = Qt + 8 * HS;

  char* ws = (char*)d_ws;
  size_t off = 0;
  auto alloc = [&](size_t bytes) { char* p = ws + off; off += (bytes + 255) & ~255ULL; return p; };
  bf16*  WT       = (bf16*)alloc(2048ULL * 512 * 2);   //  2 MB
  float* bias_all = (float*)alloc(2048 * 4);
  float* u        = (float*)alloc(64 * 4);
  bf16*  Qu       = (bf16*)alloc(8ULL * HS * 2);       // 32 MB (reused as ctxb)
  bf16*  Vj       = (bf16*)alloc(8ULL * HS * 2);       // 32 MB
  float* part     = (float*)alloc(64ULL * 65536 * 4);  // 16 MB
  float* logits   = (float*)alloc(16ULL * 65536 * 4);  //  4 MB
  float* net_bias = (float*)alloc(65536ULL * 4);
  bf16*  Pb       = (bf16*)alloc(8ULL * 65536 * 2);    //  1 MB
  bf16*  ctxb     = Qu;  // Qu dead after gemm_logits
  // total ~87.3 MB of d_ws

  const float scaling = (float)(0.125 / sqrt(128.0));  // D^-0.5 / sqrt(R)

  k_prep_w<<<4096, 256, 0, stream>>>(Wq, bq, Wk, bk, Wv, bv, Wo, bo, Wq1, Wk1,
                                     WT, bias_all, u, scaling);

  gemm_qkv<<<dim3(6, 256, 1), 512, 0, stream>>>(x, WT, bias_all, u, Qt, Kt, Qu, Vj);

  // 16 batches (8 heads + 8 u-scaled for the MLP branch), split-K=4
  gemm_logits<<<dim3(2, 2, 64), 256, 0, stream>>>(Qt, Qu, Kt, part);
  k_reduce<<<1024, 256, 0, stream>>>(part, logits);

  k_bias<<<256, 256, 0, stream>>>(logits, net, bq1, Wk1, net_bias);
  k_softmax<<<dim3(256, 8, 1), 256, 0, stream>>>(logits, net_bias, l,
                                                 out + 16777216, Pb, out + 17301504);

  // context: ctx[r,i,h,d] = sum_j P[h,i,j] Vj[h][(r,d)][j]
  gemm_bt<128, 128, 2><<<dim3(64, 2, 8), 256, 0, stream>>>(
      Pb, Vj, ctxb, nullptr, 256, 0, 65536, HS, 0);

  // output projection: [32768,512] @ Wo^T + bo -> d_out fp32
  gemm_bt<128, 128, 1><<<dim3(4, 256, 1), 256, 0, stream>>>(
      ctxb, WT + 1536 * 512, out, bias_all + 1536, 512, 512, 0, 0, 0);
}

// Round 3
// 282.956 us; speedup vs baseline: 1.0766x; 1.0766x over previous
//
#include <hip/hip_runtime.h>
#include <hip/hip_bf16.h>
#include <cmath>
#include <stdint.h>

using bf16 = __hip_bfloat16;
typedef __attribute__((ext_vector_type(8))) short bf16x8;
typedef __attribute__((ext_vector_type(4))) float f32x4;

// R=128, N=256, B=1, E=512, H=8, D=64, M=4
constexpr long HS  = 2097152;  // per-head Vj size: (R*D) * N = 8192*256
constexpr int  LDT = 40;       // LDS row stride (bf16): 80B rows, 2-way bank aliasing (free)

// ---------------- x fp32 -> bf16 (once) ----------------
__global__ __launch_bounds__(256)
void k_convert_x(const float* __restrict__ x, bf16* __restrict__ xb)
{
  const long idx = (long)blockIdx.x * 256 + threadIdx.x;  // 2,097,152 threads x 8 elems
  const float4 f0 = *(const float4*)&x[idx * 8];
  const float4 f1 = *(const float4*)&x[idx * 8 + 4];
  alignas(16) bf16 t[8] = {
    __float2bfloat16(f0.x), __float2bfloat16(f0.y),
    __float2bfloat16(f0.z), __float2bfloat16(f0.w),
    __float2bfloat16(f1.x), __float2bfloat16(f1.y),
    __float2bfloat16(f1.z), __float2bfloat16(f1.w)};
  *(uint4*)&xb[idx * 8] = *(const uint4*)t;
}

// ---------------- weight transpose via LDS tiles: WT[n][k] = W[k][n] ----------------
__global__ __launch_bounds__(256)
void k_prep_w(const float* __restrict__ Wq, const float* __restrict__ Wk,
              const float* __restrict__ Wv, const float* __restrict__ Wo,
              bf16* __restrict__ WT, float scaling)
{
  const int sel = blockIdx.z;
  const float* W = sel == 0 ? Wq : sel == 1 ? Wk : sel == 2 ? Wv : Wo;
  const float sc = sel == 0 ? scaling : 1.0f;
  const int k0 = blockIdx.x * 64, n0 = blockIdx.y * 64;
  __shared__ float tile[64][68];
  const int tid = threadIdx.x;
  #pragma unroll
  for (int it = 0; it < 4; it++) {
    const int c = tid + it * 256;           // 1024 float4 chunks
    const int kk = c >> 4, nn4 = (c & 15) * 4;
    const float4 v = *(const float4*)&W[(long)(k0 + kk) * 512 + n0 + nn4];
    tile[kk][nn4] = v.x; tile[kk][nn4 + 1] = v.y;
    tile[kk][nn4 + 2] = v.z; tile[kk][nn4 + 3] = v.w;
  }
  __syncthreads();
  #pragma unroll
  for (int it = 0; it < 2; it++) {
    const int c = tid + it * 256;           // 512 chunks of 8 along k
    const int nn = c >> 3, k8 = (c & 7) * 8;
    alignas(16) bf16 t[8];
    #pragma unroll
    for (int jj = 0; jj < 8; jj++) t[jj] = __float2bfloat16(tile[k8 + jj][nn] * sc);
    *(uint4*)&WT[(long)(sel * 512 + n0 + nn) * 512 + k0 + k8] = *(const uint4*)t;
  }
}

// bias_all (Q-scaled) and u[d] = sum_c Wq1[d,c]*Wk1[c]
__global__ void k_prep_small(const float* __restrict__ bq, const float* __restrict__ bk,
                             const float* __restrict__ bv, const float* __restrict__ bo,
                             const float* __restrict__ Wq1, const float* __restrict__ Wk1,
                             float* __restrict__ bias_all, float* __restrict__ u, float scaling)
{
  const int idx = blockIdx.x * 256 + threadIdx.x;  // 2048
  const int s2 = idx >> 9, n2 = idx & 511;
  const float* b = s2 == 0 ? bq : s2 == 1 ? bk : s2 == 2 ? bv : bo;
  bias_all[idx] = b[n2] * (s2 == 0 ? scaling : 1.0f);
  if (idx < 64) {
    float s = 0.0f;
    #pragma unroll
    for (int c = 0; c < 8; c++) s += Wq1[idx * 8 + c] * Wk1[c];
    u[idx] = s;
  }
}

// ---------------- QKV projection -> natural-layout Qn/Kn/Vn (coalesced) ----------------
// xb [32768,512] bf16; WT rows 0..1535. BM=128, BN=256, 8 waves.
__global__ __launch_bounds__(512)
void gemm_qkv(const bf16* __restrict__ xb, const bf16* __restrict__ WT,
              const float* __restrict__ bias_all,
              bf16* __restrict__ Qn, bf16* __restrict__ Kn, bf16* __restrict__ Vn)
{
  __shared__ bf16 As[128 * LDT];
  __shared__ bf16 Bs[256 * LDT];
  const int tid = threadIdx.x, lane = tid & 63, wid = tid >> 6;
  const int wr = wid >> 2, wc = wid & 3;          // 2(m) x 4(n)
  const int lr = lane & 15, lk = (lane >> 4) * 8;
  const int m0 = blockIdx.y * 128, n0 = blockIdx.x * 256;
  f32x4 acc[4][4] = {};

  for (int k0 = 0; k0 < 512; k0 += 32) {
    {
      const int r = tid >> 2, k8 = (tid & 3) * 8;  // 512 chunks
      *(uint4*)&As[r * LDT + k8] = *(const uint4*)&xb[(long)(m0 + r) * 512 + k0 + k8];
    }
    #pragma unroll
    for (int c = tid; c < 1024; c += 512) {
      const int r = c >> 2, k8 = (c & 3) * 8;
      *(uint4*)&Bs[r * LDT + k8] = *(const uint4*)&WT[(long)(n0 + r) * 512 + k0 + k8];
    }
    __syncthreads();
    bf16x8 af[4], bfr[4];
    #pragma unroll
    for (int m = 0; m < 4; m++)
      af[m] = *(const bf16x8*)&As[(wr * 64 + m * 16 + lr) * LDT + lk];
    #pragma unroll
    for (int n = 0; n < 4; n++)
      bfr[n] = *(const bf16x8*)&Bs[(wc * 64 + n * 16 + lr) * LDT + lk];
    #pragma unroll
    for (int m = 0; m < 4; m++)
      #pragma unroll
      for (int n = 0; n < 4; n++)
        acc[m][n] = __builtin_amdgcn_mfma_f32_16x16x32_bf16(af[m], bfr[n], acc[m][n], 0, 0, 0);
    __syncthreads();
  }

  const int er = (lane >> 4) * 4, ec = lane & 15;
  #pragma unroll
  for (int m = 0; m < 4; m++) {
    const int row0 = m0 + wr * 64 + m * 16 + er;
    #pragma unroll
    for (int n = 0; n < 4; n++) {
      const int col = n0 + wc * 64 + n * 16 + ec;
      const float bv = bias_all[col];
      #pragma unroll
      for (int q = 0; q < 4; q++) {
        const float v = acc[m][n][q] + bv;
        const long row = row0 + q;
        if (col < 512)       Qn[row * 512 + col]        = __float2bfloat16(v);
        else if (col < 1024) Kn[row * 512 + col - 512]  = __float2bfloat16(v);
        else                 Vn[row * 512 + col - 1024] = __float2bfloat16(v);
      }
    }
  }
}

// ---------------- logits from NATURAL layout: 16 batches x split-K=8 ----------------
// part[z][i*256+j]; z = batch*8+ks. batch<8: head logits; batch>=8: u-scaled (MLP branch).
__global__ __launch_bounds__(256)
void gemm_logits(const bf16* __restrict__ Qn, const bf16* __restrict__ Kn,
                 const float* __restrict__ u, float* __restrict__ part)
{
  __shared__ bf16 As[128 * LDT];
  __shared__ bf16 Bs[128 * LDT];
  __shared__ float us[64];
  const int z = blockIdx.z, batch = z >> 3, ks = z & 7;
  const int h = batch & 7;
  const bool uscale = batch >= 8;
  const int tid = threadIdx.x;
  if (tid < 64) us[tid] = u[tid];
  const int m0 = blockIdx.y * 128, n0 = blockIdx.x * 128;
  const int lane = tid & 63, wid = tid >> 6;
  const int wr = wid >> 1, wc = wid & 1;
  const int lr = lane & 15, lk = (lane >> 4) * 8;
  f32x4 acc[4][4] = {};
  __syncthreads();

  for (int kk = 0; kk < 1024; kk += 32) {
    const int gk = ks * 1024 + kk;
    const int r = gk >> 6, d0 = gk & 63;   // k = r*64 + d; 32-step never crosses r
    #pragma unroll
    for (int c = tid; c < 512; c += 256) {
      const int row = c >> 2, k8 = (c & 3) * 8;
      uint4 v = *(const uint4*)&Qn[((long)(r * 256 + m0 + row)) * 512 + h * 64 + d0 + k8];
      if (uscale) {
        const unsigned short* pv = (const unsigned short*)&v;
        alignas(16) bf16 t[8];
        #pragma unroll
        for (int jj = 0; jj < 8; jj++) {
          const float f = __bfloat162float(*(const bf16*)&pv[jj]) * us[d0 + k8 + jj];
          t[jj] = __float2bfloat16(f);
        }
        v = *(const uint4*)t;
      }
      *(uint4*)&As[row * LDT + k8] = v;
    }
    #pragma unroll
    for (int c = tid; c < 512; c += 256) {
      const int row = c >> 2, k8 = (c & 3) * 8;
      *(uint4*)&Bs[row * LDT + k8] =
          *(const uint4*)&Kn[((long)(r * 256 + n0 + row)) * 512 + h * 64 + d0 + k8];
    }
    __syncthreads();
    bf16x8 af[4], bfr[4];
    #pragma unroll
    for (int m = 0; m < 4; m++)
      af[m] = *(const bf16x8*)&As[(wr * 64 + m * 16 + lr) * LDT + lk];
    #pragma unroll
    for (int n = 0; n < 4; n++)
      bfr[n] = *(const bf16x8*)&Bs[(wc * 64 + n * 16 + lr) * LDT + lk];
    #pragma unroll
    for (int m = 0; m < 4; m++)
      #pragma unroll
      for (int n = 0; n < 4; n++)
        acc[m][n] = __builtin_amdgcn_mfma_f32_16x16x32_bf16(af[m], bfr[n], acc[m][n], 0, 0, 0);
    __syncthreads();
  }

  float* C = part + (long)z * 65536;
  const int er = (lane >> 4) * 4, ec = lane & 15;
  #pragma unroll
  for (int m = 0; m < 4; m++)
    #pragma unroll
    for (int n = 0; n < 4; n++) {
      const int col = n0 + wc * 64 + n * 16 + ec;
      #pragma unroll
      for (int q = 0; q < 4; q++)
        C[(long)(m0 + wr * 64 + m * 16 + er + q) * 256 + col] = acc[m][n][q];
    }
}

// ---------------- V natural -> Vj [h][(r*64+d)][j], LDS tile transpose ----------------
__global__ __launch_bounds__(256)
void k_transpose_v(const bf16* __restrict__ Vn, bf16* __restrict__ Vj)
{
  const int r = blockIdx.x, h = blockIdx.y;
  __shared__ unsigned short tile[256 * 68];
  const int tid = threadIdx.x;
  #pragma unroll
  for (int it = 0; it < 8; it++) {
    const int c = tid + it * 256;       // 2048 chunks
    const int j = c >> 3, d8 = (c & 7) * 8;
    const uint4 v = *(const uint4*)&Vn[((long)(r * 256 + j)) * 512 + h * 64 + d8];
    const unsigned short* pv = (const unsigned short*)&v;
    #pragma unroll
    for (int jj = 0; jj < 8; jj++) tile[j * 68 + d8 + jj] = pv[jj];
  }
  __syncthreads();
  #pragma unroll
  for (int it = 0; it < 8; it++) {
    const int c = tid + it * 256;
    const int d = c >> 5, j8 = (c & 31) * 8;
    alignas(16) unsigned short tmp[8];
    #pragma unroll
    for (int jj = 0; jj < 8; jj++) tmp[jj] = tile[(j8 + jj) * 68 + d];
    *(uint4*)&Vj[(long)h * HS + ((long)(r * 64 + d)) * 256 + j8] = *(const uint4*)tmp;
  }
}

// ---------------- generic C = A*B^T (bf16): MODE 1 f32 store, MODE 2 ctx scatter ----------------
template<int BM, int BN, int MODE>
__global__ __launch_bounds__((BM/64)*(BN/64)*64)
void gemm_bt(const bf16* __restrict__ A, const bf16* __restrict__ B,
             void* __restrict__ Cp, const float* __restrict__ bias,
             int K, int ldc, long sA, long sB, long sC)
{
  constexpr int NW = (BM/64)*(BN/64);
  constexpr int NT = NW * 64;
  constexpr int WC = BN/64;
  const int z = blockIdx.z;
  A += (long)z * sA;
  B += (long)z * sB;
  const int m0 = blockIdx.y * BM, n0 = blockIdx.x * BN;
  __shared__ bf16 As[BM * LDT];
  __shared__ bf16 Bs[BN * LDT];
  const int tid = threadIdx.x;
  const int lane = tid & 63, wid = tid >> 6;
  const int wr = wid / WC, wc = wid % WC;
  const int lr = lane & 15, lk = (lane >> 4) * 8;
  f32x4 acc[4][4] = {};

  for (int k0 = 0; k0 < K; k0 += 32) {
    for (int c = tid; c < BM * 4; c += NT) {
      const int r = c >> 2, k8 = (c & 3) * 8;
      *(uint4*)&As[r * LDT + k8] = *(const uint4*)&A[(long)(m0 + r) * K + k0 + k8];
    }
    for (int c = tid; c < BN * 4; c += NT) {
      const int r = c >> 2, k8 = (c & 3) * 8;
      *(uint4*)&Bs[r * LDT + k8] = *(const uint4*)&B[(long)(n0 + r) * K + k0 + k8];
    }
    __syncthreads();
    bf16x8 af[4], bfr[4];
    #pragma unroll
    for (int m = 0; m < 4; m++)
      af[m] = *(const bf16x8*)&As[(wr * 64 + m * 16 + lr) * LDT + lk];
    #pragma unroll
    for (int n = 0; n < 4; n++)
      bfr[n] = *(const bf16x8*)&Bs[(wc * 64 + n * 16 + lr) * LDT + lk];
    #pragma unroll
    for (int m = 0; m < 4; m++)
      #pragma unroll
      for (int n = 0; n < 4; n++)
        acc[m][n] = __builtin_amdgcn_mfma_f32_16x16x32_bf16(af[m], bfr[n], acc[m][n], 0, 0, 0);
    __syncthreads();
  }

  const int er = (lane >> 4) * 4, ec = lane & 15;
  #pragma unroll
  for (int m = 0; m < 4; m++) {
    #pragma unroll
    for (int n = 0; n < 4; n++) {
      const int col = n0 + wc * 64 + n * 16 + ec;
      const float bv = (MODE == 1 && bias != nullptr) ? bias[col] : 0.0f;
      #pragma unroll
      for (int q = 0; q < 4; q++) {
        const int row = m0 + wr * 64 + m * 16 + er + q;
        const float v = acc[m][n][q] + bv;
        if constexpr (MODE == 1) {
          ((float*)Cp)[z * sC + (long)row * ldc + col] = v;
        } else {
          const int rr = col >> 6, dd = col & 63;  // col = r*64+d, z = h, row = i
          ((bf16*)Cp)[(long)rr * 131072 + (long)row * 512 + z * 64 + dd] = __float2bfloat16(v);
        }
      }
    }
  }
}

// ---------------- network-bias branch (sums u-batches over h and ks) ----------------
__global__ void k_bias(const float* __restrict__ part, const float* __restrict__ network,
                       const float* __restrict__ bq1, const float* __restrict__ Wk1,
                       float* __restrict__ net_bias)
{
  const int i = blockIdx.x, j = threadIdx.x;
  float c1 = 0.0f;
  #pragma unroll
  for (int c = 0; c < 8; c++) c1 += bq1[c] * Wk1[c];
  float s1 = 0.0f;
  const long ij = i * 256 + j;
  #pragma unroll
  for (int s = 64; s < 128; s++) s1 += part[(long)s * 65536 + ij];
  s1 = 0.125f * s1 + c1;
  const float4 nw = *(const float4*)&network[ij * 4];
  const float a0 = nw.x * s1, a1 = nw.y * s1, a2 = nw.z * s1, a3 = nw.w * s1;
  const float mx = fmaxf(fmaxf(a0, a1), fmaxf(a2, a3));
  const float e0 = expf(a0 - mx), e1 = expf(a1 - mx), e2 = expf(a2 - mx), e3 = expf(a3 - mx);
  const float inv = 1.0f / (e0 + e1 + e2 + e3);
  net_bias[ij] = (nw.x * e0 + nw.y * e1 + nw.z * e2 + nw.w * e3) * inv;
}

// ---------------- row softmax (sums split-K partials), eye mask ----------------
__global__ void k_softmax(const float* __restrict__ part, const float* __restrict__ net_bias,
                          const float* __restrict__ l, float* __restrict__ out_probs,
                          bf16* __restrict__ Pb, float* __restrict__ out_l)
{
  const int i = blockIdx.x, h = blockIdx.y, j = threadIdx.x;
  const long ij = i * 256 + j;
  float w = 0.0f;
  #pragma unroll
  for (int ks = 0; ks < 8; ks++) w += part[(long)(h * 8 + ks) * 65536 + ij];
  w += l[h] * net_bias[ij];
  if (j == i) w = -1e9f;
  float m = w;
  #pragma unroll
  for (int o = 32; o; o >>= 1) m = fmaxf(m, __shfl_xor(m, o));
  __shared__ float red[4], red2[4];
  if ((j & 63) == 0) red[j >> 6] = m;
  __syncthreads();
  m = fmaxf(fmaxf(red[0], red[1]), fmaxf(red[2], red[3]));
  const float e = expf(w - m);
  float s = e;
  #pragma unroll
  for (int o = 32; o; o >>= 1) s += __shfl_xor(s, o);
  if ((j & 63) == 0) red2[j >> 6] = s;
  __syncthreads();
  s = red2[0] + red2[1] + red2[2] + red2[3];
  const float p = e / s;
  out_probs[(long)h * 65536 + ij] = p;
  Pb[(long)h * 65536 + ij] = __float2bfloat16(p);
  if (h == 0 && i == 0 && j < 8) out_l[j] = l[j];
}

extern "C" void kernel_launch(void* const* d_in, const int* in_sizes, int n_in,
                              void* d_out, int out_size, void* d_ws, size_t ws_size,
                              hipStream_t stream)
{
  const float* x   = (const float*)d_in[0];
  const float* net = (const float*)d_in[1];
  const float* Wq  = (const float*)d_in[2];
  const float* bq  = (const float*)d_in[3];
  const float* Wk  = (const float*)d_in[4];
  const float* bk  = (const float*)d_in[5];
  const float* Wv  = (const float*)d_in[6];
  const float* bv  = (const float*)d_in[7];
  const float* Wo  = (const float*)d_in[8];
  const float* bo  = (const float*)d_in[9];
  const float* Wq1 = (const float*)d_in[10];
  const float* bq1 = (const float*)d_in[11];
  const float* Wk1 = (const float*)d_in[12];
  const float* l   = (const float*)d_in[14];
  float* out = (float*)d_out;

  // d_out scratch aliasing: Qn in [0,32MB), Kn in [32,64MB); Vj overwrites Kn after logits.
  bf16* Qn = (bf16*)d_out;
  bf16* Kn = Qn + 16777216;
  bf16* Vj = Kn;

  char* ws = (char*)d_ws;
  size_t off = 0;
  auto alloc = [&](size_t bytes) { char* p = ws + off; off += (bytes + 255) & ~255ULL; return p; };
  bf16*  WT       = (bf16*)alloc(2048ULL * 512 * 2);    //  2 MB
  float* bias_all = (float*)alloc(2048 * 4);
  float* u        = (float*)alloc(64 * 4);
  bf16*  xb       = (bf16*)alloc(16777216ULL * 2);      // 32 MB; reused as `part` after QKV
  bf16*  Vn       = (bf16*)alloc(16777216ULL * 2);      // 32 MB; reused as ctxb after transpose
  float* net_bias = (float*)alloc(65536ULL * 4);        // 256 KB
  bf16*  Pb       = (bf16*)alloc(8ULL * 65536 * 2);     //  1 MB  (total ~67.5 MB)
  float* part     = (float*)xb;   // 16 batches x 8 ks x 65536 f32 = 32 MB, exact fit
  bf16*  ctxb     = Vn;

  const float scaling = (float)(0.125 / sqrt(128.0));  // D^-0.5 / sqrt(R)

  k_convert_x<<<8192, 256, 0, stream>>>(x, xb);
  k_prep_w<<<dim3(8, 8, 4), 256, 0, stream>>>(Wq, Wk, Wv, Wo, WT, scaling);
  k_prep_small<<<8, 256, 0, stream>>>(bq, bk, bv, bo, Wq1, Wk1, bias_all, u, scaling);

  gemm_qkv<<<dim3(6, 256, 1), 512, 0, stream>>>(xb, WT, bias_all, Qn, Kn, Vn);

  gemm_logits<<<dim3(2, 2, 128), 256, 0, stream>>>(Qn, Kn, u, part);

  k_transpose_v<<<dim3(128, 8, 1), 256, 0, stream>>>(Vn, Vj);

  k_bias<<<256, 256, 0, stream>>>(part, net, bq1, Wk1, net_bias);
  k_softmax<<<dim3(256, 8, 1), 256, 0, stream>>>(part, net_bias, l,
                                                 out + 16777216, Pb, out + 17301504);

  // context: ctx[r,i,h,d] = sum_j P[h,i,j] Vj[h][(r,d)][j]
  gemm_bt<128, 128, 2><<<dim3(64, 2, 8), 256, 0, stream>>>(
      Pb, Vj, ctxb, nullptr, 256, 0, 65536, HS, 0);

  // output projection: [32768,512] @ Wo^T + bo -> d_out fp32
  gemm_bt<128, 128, 1><<<dim3(4, 256, 1), 256, 0, stream>>>(
      ctxb, WT + 1536 * 512, out, bias_all + 1536, 512, 512, 0, 0, 0);
}